// Round 1
// baseline (2565.735 us; speedup 1.0000x reference)
//
#include <hip/hip_runtime.h>

#define NN 20000
#define NE 640000
#define DSH 9
#define NB 10
#define M1 64
#define M2 128
#define ATTR 4
#define EPW 16   // edges per wave-iteration (NE % EPW == 0)

constexpr float INV_SQRT_NB = 0.17677669529663687f; // 1/sqrt(32)

__device__ __forceinline__ float silu_f(float x) {
    return x / (1.0f + __expf(-x));
}

__device__ __forceinline__ void load16(float* v, const float* p) {
    const float4* q = (const float4*)p;
    float4 a = q[0], b = q[1], c = q[2], d = q[3];
    v[0]=a.x; v[1]=a.y; v[2]=a.z; v[3]=a.w;
    v[4]=b.x; v[5]=b.y; v[6]=b.z; v[7]=b.w;
    v[8]=c.x; v[9]=c.y; v[10]=c.z; v[11]=c.w;
    v[12]=d.x; v[13]=d.y; v[14]=d.z; v[15]=d.w;
}

// ---------------------------------------------------------------------------
// Per-node prep: xa = x @ A   and   agg = outer(x, attr) @ Wsc  (self-conn)
// ---------------------------------------------------------------------------
template<int DI, int DO, int NT>
__global__ void node_prep(const float* __restrict__ xin,
                          const float* __restrict__ attr,
                          const float* __restrict__ A,
                          const float* __restrict__ Wsc,
                          float* __restrict__ xa,
                          float* __restrict__ agg)
{
    __shared__ float sx[NT][DI];
    __shared__ float sat[NT][ATTR];
    const int n0 = blockIdx.x * NT;
    for (int idx = threadIdx.x; idx < NT * DI; idx += blockDim.x)
        sx[idx / DI][idx % DI] = xin[(size_t)n0 * DI + idx];
    if (threadIdx.x < NT * ATTR)
        sat[threadIdx.x / ATTR][threadIdx.x % ATTR] = attr[(size_t)n0 * ATTR + threadIdx.x];
    __syncthreads();

    const int o = threadIdx.x;
    if (o < DO) {
        float at[NT][ATTR];
        #pragma unroll
        for (int n = 0; n < NT; n++) {
            at[n][0] = sat[n][0]; at[n][1] = sat[n][1];
            at[n][2] = sat[n][2]; at[n][3] = sat[n][3];
        }
        float accA[NT], accS[NT];
        #pragma unroll
        for (int n = 0; n < NT; n++) { accA[n] = 0.f; accS[n] = 0.f; }
        for (int i = 0; i < DI; i++) {
            float a  = A[(size_t)i * DO + o];
            float w0 = Wsc[(size_t)(i * 4 + 0) * DO + o];
            float w1 = Wsc[(size_t)(i * 4 + 1) * DO + o];
            float w2 = Wsc[(size_t)(i * 4 + 2) * DO + o];
            float w3 = Wsc[(size_t)(i * 4 + 3) * DO + o];
            #pragma unroll
            for (int n = 0; n < NT; n++) {
                float xi = sx[n][i];
                accA[n] = fmaf(xi, a, accA[n]);
                float s = fmaf(at[n][3], w3,
                          fmaf(at[n][2], w2,
                          fmaf(at[n][1], w1, at[n][0] * w0)));
                accS[n] = fmaf(xi, s, accS[n]);
            }
        }
        #pragma unroll
        for (int n = 0; n < NT; n++) {
            xa [(size_t)(n0 + n) * DO + o] = accA[n];
            agg[(size_t)(n0 + n) * DO + o] = accS[n];
        }
    }
}

// ---------------------------------------------------------------------------
// Fused edge kernel: radial MLP + tensor-product message + atomic scatter.
// One wave processes EPW=16 edges per iteration. h1/h2 tiles transposed in
// LDS ([k][e]) so the GEMM inner loops read them as broadcast float4s.
// ---------------------------------------------------------------------------
struct alignas(16) WaveBuf {
    float embT[NB * EPW];   // [10][16]
    float shT [DSH * EPW];  // [9][16]
    float h1T [M1 * EPW];   // [64][16]
    float h2T [M2 * EPW];   // [128][16]
    int   sidx[EPW];
    int   didx[EPW];
};

template<int DO>
__global__ void __launch_bounds__(256, 2)
edge_mp(const float* __restrict__ emb,  // [E,10]
        const float* __restrict__ sh,   // [E,9]
        const int*   __restrict__ src,
        const int*   __restrict__ dst,
        const float* __restrict__ W1g,  // [10][64]
        const float* __restrict__ W2g,  // [64][128]
        const float* __restrict__ W3g,  // [128][DO]
        const float* __restrict__ Bg,   // [9][DO]
        const float* __restrict__ xa,   // [N,DO]
        float* __restrict__ agg)        // [N,DO]
{
    __shared__ float sW1[NB * M1];
    __shared__ WaveBuf wb[4];
    for (int idx = threadIdx.x; idx < NB * M1; idx += blockDim.x)
        sW1[idx] = W1g[idx];
    __syncthreads();

    const int wid  = threadIdx.x >> 6;
    const int lane = threadIdx.x & 63;
    WaveBuf& wbuf = wb[wid];
    const int gwave = blockIdx.x * 4 + wid;
    const int nwave = gridDim.x * 4;
    const int niter = NE / EPW;

    for (int it = gwave; it < niter; it += nwave) {
        const int e0 = it * EPW;
        // ---- stage emb/sh/idx for 16 edges into transposed LDS tiles ----
        {
            const float* ep = emb + (size_t)e0 * NB;
            int f = lane;        wbuf.embT[(f % 10) * EPW + f / 10] = ep[f];
            f = lane + 64;       wbuf.embT[(f % 10) * EPW + f / 10] = ep[f];
            if (lane < 32) { f = lane + 128; wbuf.embT[(f % 10) * EPW + f / 10] = ep[f]; }
            const float* sp = sh + (size_t)e0 * DSH;
            f = lane;            wbuf.shT[(f % 9) * EPW + f / 9] = sp[f];
            f = lane + 64;       wbuf.shT[(f % 9) * EPW + f / 9] = sp[f];
            if (lane < 16) { f = lane + 128; wbuf.shT[(f % 9) * EPW + f / 9] = sp[f]; }
            if (lane < EPW) {
                wbuf.sidx[lane] = src[e0 + lane];
                wbuf.didx[lane] = dst[e0 + lane];
            }
        }
        // ---- phase A: h1 = silu(emb @ W1), lane = hidden unit j ----
        {
            float hacc[EPW];
            #pragma unroll
            for (int e = 0; e < EPW; e++) hacc[e] = 0.f;
            #pragma unroll
            for (int k = 0; k < NB; k++) {
                float w = sW1[k * M1 + lane];
                float ev[EPW]; load16(ev, &wbuf.embT[k * EPW]);
                #pragma unroll
                for (int e = 0; e < EPW; e++) hacc[e] = fmaf(ev[e], w, hacc[e]);
            }
            #pragma unroll
            for (int q = 0; q < 4; q++) {
                float4 o4;
                o4.x = silu_f(hacc[4*q+0]); o4.y = silu_f(hacc[4*q+1]);
                o4.z = silu_f(hacc[4*q+2]); o4.w = silu_f(hacc[4*q+3]);
                ((float4*)&wbuf.h1T[lane * EPW])[q] = o4;
            }
        }
        // ---- phase B: h2 = silu(h1 @ W2), lane owns j = lane, lane+64 ----
        {
            float b0[EPW], b1[EPW];
            #pragma unroll
            for (int e = 0; e < EPW; e++) { b0[e] = 0.f; b1[e] = 0.f; }
            #pragma unroll 4
            for (int k = 0; k < M1; k++) {
                float w2a = W2g[k * M2 + lane];
                float w2b = W2g[k * M2 + 64 + lane];
                float hv[EPW]; load16(hv, &wbuf.h1T[k * EPW]);
                #pragma unroll
                for (int e = 0; e < EPW; e++) {
                    b0[e] = fmaf(hv[e], w2a, b0[e]);
                    b1[e] = fmaf(hv[e], w2b, b1[e]);
                }
            }
            #pragma unroll
            for (int q = 0; q < 4; q++) {
                float4 o4;
                o4.x = silu_f(b0[4*q+0]); o4.y = silu_f(b0[4*q+1]);
                o4.z = silu_f(b0[4*q+2]); o4.w = silu_f(b0[4*q+3]);
                ((float4*)&wbuf.h2T[lane * EPW])[q] = o4;
                o4.x = silu_f(b1[4*q+0]); o4.y = silu_f(b1[4*q+1]);
                o4.z = silu_f(b1[4*q+2]); o4.w = silu_f(b1[4*q+3]);
                ((float4*)&wbuf.h2T[(64 + lane) * EPW])[q] = o4;
            }
        }

        if constexpr (DO == 3) {
            // ---- small-output path (layer 2): lane -> (edge, o) ----
            const bool act = lane < 48;
            int e = lane / 3;
            int o = lane - 3 * e;
            if (!act) { e = 0; o = 0; }
            float gacc = 0.f, sacc = 0.f;
            #pragma unroll 4
            for (int k = 0; k < M2; k++)
                gacc = fmaf(wbuf.h2T[k * EPW + e], W3g[k * 3 + o], gacc);
            #pragma unroll
            for (int k = 0; k < DSH; k++)
                sacc = fmaf(wbuf.shT[k * EPW + e], Bg[k * 3 + o], sacc);
            if (act) {
                int sN = wbuf.sidx[e], dN = wbuf.didx[e];
                float m = gacc * sacc * xa[(size_t)sN * 3 + o];
                atomicAdd(&agg[(size_t)dN * 3 + o], m * INV_SQRT_NB);
            }
        } else {
            // ---- phase C: gate = h2 @ W3, lane owns o = lane, lane+64, lane+128 ----
            const int o3 = 128 + lane;
            float g0[EPW], g1[EPW], g2[EPW];
            #pragma unroll
            for (int e = 0; e < EPW; e++) { g0[e]=0.f; g1[e]=0.f; g2[e]=0.f; }
            #pragma unroll 2
            for (int k = 0; k < M2; k++) {
                float w3a = W3g[(size_t)k * DO + lane];
                float w3b = W3g[(size_t)k * DO + 64 + lane];
                float w3c = (o3 < DO) ? W3g[(size_t)k * DO + o3] : 0.f;
                float hv[EPW]; load16(hv, &wbuf.h2T[k * EPW]);
                #pragma unroll
                for (int e = 0; e < EPW; e++) {
                    g0[e] = fmaf(hv[e], w3a, g0[e]);
                    g1[e] = fmaf(hv[e], w3b, g1[e]);
                    g2[e] = fmaf(hv[e], w3c, g2[e]);
                }
            }
            // ---- phase D: shb = sh @ B ----
            float s0[EPW], s1[EPW], s2[EPW];
            #pragma unroll
            for (int e = 0; e < EPW; e++) { s0[e]=0.f; s1[e]=0.f; s2[e]=0.f; }
            #pragma unroll
            for (int k = 0; k < DSH; k++) {
                float ba = Bg[(size_t)k * DO + lane];
                float bb = Bg[(size_t)k * DO + 64 + lane];
                float bc = (o3 < DO) ? Bg[(size_t)k * DO + o3] : 0.f;
                float sv[EPW]; load16(sv, &wbuf.shT[k * EPW]);
                #pragma unroll
                for (int e = 0; e < EPW; e++) {
                    s0[e] = fmaf(sv[e], ba, s0[e]);
                    s1[e] = fmaf(sv[e], bb, s1[e]);
                    s2[e] = fmaf(sv[e], bc, s2[e]);
                }
            }
            // ---- gather xa[src], combine, atomic scatter to agg[dst] ----
            #pragma unroll
            for (int e = 0; e < EPW; e++) {
                int sN = wbuf.sidx[e], dN = wbuf.didx[e];
                const float* xr = xa + (size_t)sN * DO;
                float* ar = agg + (size_t)dN * DO;
                atomicAdd(&ar[lane],      g0[e] * s0[e] * xr[lane]      * INV_SQRT_NB);
                atomicAdd(&ar[64 + lane], g1[e] * s1[e] * xr[64 + lane] * INV_SQRT_NB);
                if (o3 < DO)
                    atomicAdd(&ar[o3],    g2[e] * s2[e] * xr[o3]        * INV_SQRT_NB);
            }
        }
    }
}

__global__ void silu_kernel(const float* __restrict__ in, float* __restrict__ out, int n)
{
    int i = blockIdx.x * blockDim.x + threadIdx.x;
    int st = gridDim.x * blockDim.x;
    for (; i < n; i += st) out[i] = silu_f(in[i]);
}

// ---------------------------------------------------------------------------
extern "C" void kernel_launch(void* const* d_in, const int* in_sizes, int n_in,
                              void* d_out, int out_size, void* d_ws, size_t ws_size,
                              hipStream_t stream) {
    const float* x    = (const float*)d_in[0];
    const float* attr = (const float*)d_in[1];
    const float* sh   = (const float*)d_in[2];
    const float* emb  = (const float*)d_in[3];
    const float* A0   = (const float*)d_in[4];
    const float* B0   = (const float*)d_in[5];
    const float* W1_0 = (const float*)d_in[6];
    const float* W2_0 = (const float*)d_in[7];
    const float* W3_0 = (const float*)d_in[8];
    const float* Wsc0 = (const float*)d_in[9];
    const float* A1   = (const float*)d_in[10];
    const float* B1   = (const float*)d_in[11];
    const float* W1_1 = (const float*)d_in[12];
    const float* W2_1 = (const float*)d_in[13];
    const float* W3_1 = (const float*)d_in[14];
    const float* Wsc1 = (const float*)d_in[15];
    const float* A2   = (const float*)d_in[16];
    const float* B2   = (const float*)d_in[17];
    const float* W1_2 = (const float*)d_in[18];
    const float* W2_2 = (const float*)d_in[19];
    const float* W3_2 = (const float*)d_in[20];
    const float* Wsc2 = (const float*)d_in[21];
    const int*   src  = (const int*)d_in[22];
    const int*   dst  = (const int*)d_in[23];
    float* out = (float*)d_out;

    float* ws   = (float*)d_ws;
    float* hb0  = ws;                         // [N,144]
    float* hb1  = ws + (size_t)NN * 144;      // [N,144]
    float* xa   = ws + (size_t)2 * NN * 144;  // [N,144]
    float* agg  = ws + (size_t)3 * NN * 144;  // [N,144]

    // ---- layer 0 (di=64, do=144) ----
    node_prep<64, 144, 8><<<NN / 8, 192, 0, stream>>>(x, attr, A0, Wsc0, xa, agg);
    edge_mp<144><<<512, 256, 0, stream>>>(emb, sh, src, dst, W1_0, W2_0, W3_0, B0, xa, agg);
    silu_kernel<<<2048, 256, 0, stream>>>(agg, hb0, NN * 144);

    // ---- layer 1 (di=144, do=144) ----
    node_prep<144, 144, 8><<<NN / 8, 192, 0, stream>>>(hb0, attr, A1, Wsc1, xa, agg);
    edge_mp<144><<<512, 256, 0, stream>>>(emb, sh, src, dst, W1_1, W2_1, W3_1, B1, xa, agg);
    silu_kernel<<<2048, 256, 0, stream>>>(agg, hb1, NN * 144);

    // ---- layer 2 (di=144, do=3), writes straight into d_out ----
    node_prep<144, 3, 8><<<NN / 8, 192, 0, stream>>>(hb1, attr, A2, Wsc2, xa, out);
    edge_mp<3><<<512, 256, 0, stream>>>(emb, sh, src, dst, W1_2, W2_2, W3_2, B2, xa, out);
}